// Round 6
// baseline (166.161 us; speedup 1.0000x reference)
//
#include <hip/hip_runtime.h>

// AtlasAttention v7 — race-free counted-vmcnt pipeline.
// Window order: WAIT(vmcnt N, lgkm 0)+barrier -> stage(g+2) -> ds_read(g) -> MFMA.
//  * stage after barrier => 3-slot ring is race-free (slot (g+2)%3's readers
//    finished before the barrier; lgkmcnt(0) in the macro guarantees it).
//  * counted vmcnt keeps 1-2 chunks in flight across barriers (T3+T4).
//
// ws layout (bytes):
//   Xb   @ 0          : 8192*768 bf16   = 12,582,912
//   Wqb  @ 12,582,912 : 768*768  bf16^T = 1,179,648   (Wqb[n][k])
//   W1b  @ 13,762,560 : 512*256  bf16^T = 262,144     (W1b[n][k])
//   W2b  @ 14,024,704 : 64*512   bf16^T = 65,536      (W2b[m][k])
//   b1e  @ 14,090,240 : 512 f32         = 2,048
//   P    @ 14,092,288 : 98304*192 bf16  = 37,748,736  -> ends 51,841,024 (ws >= 114MB)

typedef unsigned short u16;
typedef __attribute__((ext_vector_type(8))) short short8;
typedef __attribute__((ext_vector_type(4))) float f32x4;
typedef __attribute__((ext_vector_type(4))) u16 u16x4;

__device__ __forceinline__ u16 f2bf(float f) {
    unsigned u = __builtin_bit_cast(unsigned, f);
    u += 0x7FFFu + ((u >> 16) & 1u);   // RNE
    return (u16)(u >> 16);
}

__device__ __forceinline__ unsigned cvtpk_bf16(float lo, float hi) {
    unsigned r;
    asm("v_cvt_pk_bf16_f32 %0, %1, %2" : "=v"(r) : "v"(lo), "v"(hi));
    return r;
}

__device__ __forceinline__ void gl2lds16(const void* g, void* l) {
    __builtin_amdgcn_global_load_lds(
        (const __attribute__((address_space(1))) unsigned int*)g,
        (__attribute__((address_space(3))) unsigned int*)l, 16, 0, 0);
}

// barrier macros: lgkmcnt(0) ALWAYS included so a wave's LDS reads are complete
// before it passes any barrier (closes the MFMA-sinking hole, rule #18).
#define WAIT_VM_LGKM_BAR(N) \
    asm volatile("s_waitcnt vmcnt(" #N ") lgkmcnt(0)\n\ts_barrier" ::: "memory")
#define WAIT_LGKM_BAR() \
    asm volatile("s_waitcnt lgkmcnt(0)\n\ts_barrier" ::: "memory")

// ---------------- fused prep kernel ----------------
// grid 6882 x 256:
//   [0,6144)     cast X      [6144,6720) transpose Wq   [6720,6848) transpose W1
//   [6848,6880)  transpose W2  [6880,6882) b1e

__global__ __launch_bounds__(256)
void prep(const float* __restrict__ X, u16* __restrict__ Xb,
          const float* __restrict__ Wq, u16* __restrict__ Wqb,
          const float* __restrict__ W1, u16* __restrict__ W1b,
          const float* __restrict__ W2, u16* __restrict__ W2b,
          const float* __restrict__ b1, const float* __restrict__ coeffs,
          float* __restrict__ b1e)
{
    __shared__ float t[32][33];
    const int b = blockIdx.x, tid = threadIdx.x;

    if (b < 6144) {                       // ---- cast X ----
        const int i = b * 256 + tid;
        float4 v = reinterpret_cast<const float4*>(X)[i];
        u16x4 o = {f2bf(v.x), f2bf(v.y), f2bf(v.z), f2bf(v.w)};
        reinterpret_cast<u16x4*>(Xb)[i] = o;
    } else if (b < 6880) {                // ---- transposes ----
        const float* in; u16* out; int R, Cin, bx, by;
        int lb = b - 6144;
        if (lb < 576)      { in = Wq; out = Wqb; R = 768; Cin = 768; bx = lb % 24; by = lb / 24; }
        else if (lb < 704) { lb -= 576; in = W1; out = W1b; R = 256; Cin = 512; bx = lb % 16; by = lb / 16; }
        else               { lb -= 704; in = W2; out = W2b; R = 512; Cin = 256; bx = lb % 2;  by = lb / 2; }
        const int c0 = bx * 32, r0 = by * 32;
        const int tx = tid & 31, ty = tid >> 5;
        #pragma unroll
        for (int j = 0; j < 32; j += 8)
            t[ty + j][tx] = in[(size_t)(r0 + ty + j) * Cin + c0 + tx];
        __syncthreads();
        #pragma unroll
        for (int j = 0; j < 32; j += 8)
            out[(size_t)(c0 + ty + j) * R + r0 + tx] = f2bf(t[tx][ty + j]);
    } else {                              // ---- b1e ----
        const int n = (b - 6880) * 256 + tid;
        float s = 0.f;
        #pragma unroll 8
        for (int k = 0; k < 64; ++k) s += W1[k * 512 + n];
        b1e[n] = b1[n] + coeffs[0] * s;
    }
}

// ---------------- GEMM1 + poly epilogue ----------------
// Block: 64 tokens x 128 n-cols (2 heads). grid (128, 6) = 768 blocks.
// 3-slot ring, stage AFTER wait+barrier, uniform vmcnt(3) (3 loads/chunk,
// exactly one newer chunk in flight at each wait).

__global__ __launch_bounds__(256, 3)
void gemm1_poly(const u16* __restrict__ Xb, const u16* __restrict__ Wqb,
                const float* __restrict__ coeffs, u16* __restrict__ P)
{
    __shared__ u16 lds[128 * 200];   // 51.2KB; ring = 3 x 6144 u16 in first 36KB

    const int tid = threadIdx.x;
    const int w = tid >> 6, lane = tid & 63;
    const int lrow = lane >> 2, lslot = lane & 3;
    const int m16 = lane & 15, quad = lane >> 4;
    const int w0 = w & 1, w1 = w >> 1;
    const int tok0 = blockIdx.x * 64;
    const int bn = blockIdx.y * 128;
    const int h0 = blockIdx.y * 2;

    const float c1 = coeffs[1], c2 = coeffs[2], c3 = coeffs[3];

    f32x4 acc[4][2];
    #pragma unroll
    for (int i = 0; i < 4; ++i)
        #pragma unroll
        for (int j = 0; j < 2; ++j)
            acc[i][j] = (f32x4){0.f, 0.f, 0.f, 0.f};

    auto stage = [&](int slot, int g) {   // 3 loads/thread
        const int k0 = g * 32;
        u16* Xs = lds + slot * 6144;      // [64][32]
        u16* Ws = Xs + 2048;              // [128][32]
        {
            const int row = w * 16 + lrow;
            const int cc = lslot ^ ((row >> 2) & 3);
            gl2lds16(Xb + (size_t)(tok0 + row) * 768 + k0 + cc * 8, &Xs[row * 32 + lslot * 8]);
        }
        #pragma unroll
        for (int i = 0; i < 2; ++i) {
            const int row = (w * 2 + i) * 16 + lrow;
            const int cc = lslot ^ ((row >> 2) & 3);
            gl2lds16(Wqb + (size_t)(bn + row) * 768 + k0 + cc * 8, &Ws[row * 32 + lslot * 8]);
        }
    };

    stage(0, 0);
    stage(1, 1);

    #pragma unroll 1
    for (int g = 0; g < 24; ++g) {
        WAIT_VM_LGKM_BAR(3);                          // chunk g landed; readers of g-1 done
        const int gg = (g + 2 <= 23) ? g + 2 : 23;    // tail: dummy re-stage of 23
        stage((g + 2) % 3, gg);                       // slot (g-1)%3: safe post-barrier
        const u16* Xs = lds + (g % 3) * 6144;
        const u16* Ws = Xs + 2048;
        short8 a[4], b[2];
        #pragma unroll
        for (int i = 0; i < 4; ++i) {
            const int row = w0 * 64 + i * 16 + m16;    // n local
            const int ss = quad ^ ((row >> 2) & 3);
            a[i] = *reinterpret_cast<const short8*>(&Ws[row * 32 + ss * 8]);
        }
        #pragma unroll
        for (int j = 0; j < 2; ++j) {
            const int row = w1 * 32 + j * 16 + m16;    // token local
            const int ss = quad ^ ((row >> 2) & 3);
            b[j] = *reinterpret_cast<const short8*>(&Xs[row * 32 + ss * 8]);
        }
        #pragma unroll
        for (int i = 0; i < 4; ++i)
            #pragma unroll
            for (int j = 0; j < 2; ++j)
                acc[i][j] = __builtin_amdgcn_mfma_f32_16x16x32_bf16(a[i], b[j], acc[i][j], 0, 0, 0);
    }

    // drain dummy stages before bounce overwrites the ring region
    asm volatile("s_waitcnt vmcnt(0) lgkmcnt(0)\n\ts_barrier" ::: "memory");

    // ---- poly epilogue: pack 4 consecutive d per lane -> uint2 LDS writes ----
    #pragma unroll
    for (int i = 0; i < 4; ++i) {
        const int d0 = i * 16 + quad * 4;
        #pragma unroll
        for (int j = 0; j < 2; ++j) {
            const int tokLocal = w1 * 32 + j * 16 + m16;
            u16* base = &lds[(tokLocal * 2 + w0) * 200 + d0];
            float x[4], x2[4];
            #pragma unroll
            for (int r = 0; r < 4; ++r) {
                x[r] = fminf(fmaxf(acc[i][j][r], -10.f), 10.f);
                x2[r] = x[r] * x[r];
            }
            uint2 p1, p2, p3;
            p1.x = cvtpk_bf16(c1 * x[0], c1 * x[1]);
            p1.y = cvtpk_bf16(c1 * x[2], c1 * x[3]);
            p2.x = cvtpk_bf16(c2 * x2[0], c2 * x2[1]);
            p2.y = cvtpk_bf16(c2 * x2[2], c2 * x2[3]);
            p3.x = cvtpk_bf16(c3 * x2[0] * x[0], c3 * x2[1] * x[1]);
            p3.y = cvtpk_bf16(c3 * x2[2] * x[2], c3 * x2[3] * x[3]);
            *reinterpret_cast<uint2*>(base)       = p1;
            *reinterpret_cast<uint2*>(base + 64)  = p2;
            *reinterpret_cast<uint2*>(base + 128) = p3;
        }
    }
    __syncthreads();

    // ---- cooperative coalesced store: 12 x dwordx4 per thread ----
    #pragma unroll
    for (int ii = 0; ii < 12; ++ii) {
        const int flat = ii * 256 + tid;       // 0..3071
        const int rowL = flat / 24, ck = flat % 24;
        const int tokL = rowL >> 1, hh = rowL & 1;
        const size_t prow = ((size_t)(tok0 + tokL) * 12 + h0 + hh);
        short8 v = *reinterpret_cast<const short8*>(&lds[rowL * 200 + ck * 8]);
        *reinterpret_cast<short8*>(P + prow * 192 + ck * 8) = v;
    }
}

// ---------------- fused GEMM2+GEMM3 (race-free pipelined) ----------------
// Per block (256 thr, 4 waves): 128 token-rows. 24 K-chunks (4 slices x 6).
// Ring 3 x (W1[128][32] + P[128][32]) = 48KB; Hs 32KB -> 80KB, 2 blocks/CU.
// W2 fragments in registers, loaded at each slice's first window (8 vmem ops);
// per-slice wait schedule [4,12,4,4,4,4] is robust to compiler reordering of
// the W2 loads within their window.

__global__ __launch_bounds__(256, 2)
void gemm23(const u16* __restrict__ P, const u16* __restrict__ W1t,
            const float* __restrict__ b1e, const u16* __restrict__ W2t,
            const float* __restrict__ b2, float* __restrict__ out)
{
    __shared__ u16 ring[3][8192];     // per slot: W1 @0, P @4096
    __shared__ u16 Hs[4][128 * 32];   // H slice, token-major, swizzled slots

    const int tid = threadIdx.x;
    const int w = tid >> 6, lane = tid & 63;
    const int lrow = lane >> 2, lslot = lane & 3;
    const int m16 = lane & 15, quad = lane >> 4;
    const size_t r0 = (size_t)blockIdx.x * 128;
    const int w0 = w & 1, w1 = w >> 1;

    auto stageTo = [&](int slot, int g) {   // 4 loads/thread
        const int s = g / 6, c = g % 6;
        u16* W1s = ring[slot];
        u16* Ps  = ring[slot] + 4096;
        #pragma unroll
        for (int i = 0; i < 2; ++i) {
            const int row = (w * 2 + i) * 16 + lrow;
            const int cc = lslot ^ ((row >> 2) & 3);
            gl2lds16(W1t + (size_t)(s * 128 + row) * 256 + 64 + c * 32 + cc * 8,
                     &W1s[row * 32 + lslot * 8]);
            gl2lds16(P + (r0 + row) * 192 + c * 32 + cc * 8,
                     &Ps[row * 32 + lslot * 8]);
        }
    };
    auto stageClamped = [&](int slot, int gg) {
        if (gg <= 23) stageTo(slot, gg);
        else if (gg == 24) stageTo(slot, 23);   // dummy keeps vmcnt uniform; slot dead
    };

    short8 b3s[4][2];                 // W2 fragments for current slice (8 vmem loads)
    auto loadW2 = [&](int s) {
        #pragma unroll
        for (int c = 0; c < 4; ++c)
            #pragma unroll
            for (int j = 0; j < 2; ++j)
                b3s[c][j] = *reinterpret_cast<const short8*>(
                    W2t + (size_t)(w1 * 32 + j * 16 + m16) * 512 + s * 128 + c * 32 + quad * 8);
    };

    f32x4 accO[4][2];
    #pragma unroll
    for (int i = 0; i < 4; ++i)
        #pragma unroll
        for (int j = 0; j < 2; ++j)
            accO[i][j] = (f32x4){0.f, 0.f, 0.f, 0.f};

    stageTo(0, 0);
    stageTo(1, 1);

    #pragma unroll 1
    for (int s = 0; s < 4; ++s) {
        f32x4 accH[4][4];
        #pragma unroll
        for (int i = 0; i < 4; ++i)
            #pragma unroll
            for (int j = 0; j < 4; ++j)
                accH[i][j] = (f32x4){0.f, 0.f, 0.f, 0.f};

        auto computeH = [&](int slot) {
            const u16* W1s = ring[slot];
            const u16* Ps  = ring[slot] + 4096;
            short8 af[4], bf[4];
            #pragma unroll
            for (int i = 0; i < 4; ++i) {
                const int row = w0 * 64 + i * 16 + m16;          // nH local
                const int ss = quad ^ ((row >> 2) & 3);
                af[i] = *reinterpret_cast<const short8*>(&W1s[row * 32 + ss * 8]);
            }
            #pragma unroll
            for (int j = 0; j < 4; ++j) {
                const int row = w1 * 64 + j * 16 + m16;          // token local
                const int ss = quad ^ ((row >> 2) & 3);
                bf[j] = *reinterpret_cast<const short8*>(&Ps[row * 32 + ss * 8]);
            }
            #pragma unroll
            for (int i = 0; i < 4; ++i)
                #pragma unroll
                for (int j = 0; j < 4; ++j)
                    accH[i][j] = __builtin_amdgcn_mfma_f32_16x16x32_bf16(af[i], bf[j], accH[i][j], 0, 0, 0);
        };

        const int g0 = s * 6;
        // windows c6 = 0..5; read slot = c6%3, stage slot = (c6+2)%3 (6s = 0 mod 3)
        WAIT_VM_LGKM_BAR(4);  stageClamped(2, g0 + 2); loadW2(s); computeH(0);
        WAIT_VM_LGKM_BAR(12); stageClamped(0, g0 + 3);            computeH(1);
        WAIT_VM_LGKM_BAR(4);  stageClamped(1, g0 + 4);            computeH(2);
        WAIT_VM_LGKM_BAR(4);  stageClamped(2, g0 + 5);            computeH(0);
        WAIT_VM_LGKM_BAR(4);  stageClamped(0, g0 + 6);            computeH(1);
        WAIT_VM_LGKM_BAR(4);  stageClamped(1, g0 + 7);            computeH(2);

        // ---- drain: Hs[token][nH] = bf16(relu(accH + b1e)); 8B k-contiguous writes ----
        #pragma unroll
        for (int i = 0; i < 4; ++i) {
            const int lb = w0 * 64 + i * 16 + quad * 4;          // nH local base
            const f32x4 bv = *reinterpret_cast<const f32x4*>(&b1e[s * 128 + lb]);
            const int hc = lb >> 5;
            #pragma unroll
            for (int j = 0; j < 4; ++j) {
                const int tc = w1 * 64 + j * 16 + m16;           // token local
                const float h0 = fmaxf(accH[i][j][0] + bv[0], 0.f);
                const float h1 = fmaxf(accH[i][j][1] + bv[1], 0.f);
                const float h2 = fmaxf(accH[i][j][2] + bv[2], 0.f);
                const float h3 = fmaxf(accH[i][j][3] + bv[3], 0.f);
                uint2 v;
                v.x = cvtpk_bf16(h0, h1);
                v.y = cvtpk_bf16(h2, h3);
                const int sl = ((lb >> 3) & 3) ^ ((tc >> 2) & 3);
                *reinterpret_cast<uint2*>(&Hs[hc][tc * 32 + sl * 8 + (lb & 7)]) = v;
            }
        }

        WAIT_LGKM_BAR();   // Hs visible; ring prefetches stay in flight

        // ---- GEMM3 partial: accO += Hs @ W2slice^T (W2 frags in regs) ----
        #pragma unroll
        for (int c = 0; c < 4; ++c) {
            short8 a3[4];
            #pragma unroll
            for (int i = 0; i < 4; ++i) {
                const int tr = w0 * 64 + i * 16 + m16;           // token local
                const int ss = quad ^ ((tr >> 2) & 3);
                a3[i] = *reinterpret_cast<const short8*>(&Hs[c][tr * 32 + ss * 8]);
            }
            #pragma unroll
            for (int i = 0; i < 4; ++i)
                #pragma unroll
                for (int j = 0; j < 2; ++j)
                    accO[i][j] = __builtin_amdgcn_mfma_f32_16x16x32_bf16(a3[i], b3s[c][j], accO[i][j], 0, 0, 0);
        }
        // no trailing barrier: next slice's first WAIT_VM_LGKM_BAR (with lgkm 0)
        // guarantees these ds_reads complete before any wave's next drain.
    }

    asm volatile("s_waitcnt vmcnt(0)" ::: "memory");   // retire dummy stages

    // ---- epilogue: out[r0+row][col] = accO + b2 ----
    #pragma unroll
    for (int j = 0; j < 2; ++j) {
        const int col = w1 * 32 + j * 16 + m16;
        const float bv = b2[col];
        #pragma unroll
        for (int i = 0; i < 4; ++i) {
            #pragma unroll
            for (int r = 0; r < 4; ++r) {
                const int row = w0 * 64 + i * 16 + quad * 4 + r;
                out[(r0 + row) * 64 + col] = accO[i][j][r] + bv;
            }
        }
    }
}

// ---------------- host ----------------

extern "C" void kernel_launch(void* const* d_in, const int* in_sizes, int n_in,
                              void* d_out, int out_size, void* d_ws, size_t ws_size,
                              hipStream_t stream) {
    const float* X      = (const float*)d_in[0];
    const float* Wq     = (const float*)d_in[1];
    const float* coeffs = (const float*)d_in[2];
    const float* W1     = (const float*)d_in[3];
    const float* b1     = (const float*)d_in[4];
    const float* W2     = (const float*)d_in[5];
    const float* b2     = (const float*)d_in[6];

    char* ws = (char*)d_ws;
    u16*   Xb  = (u16*)(ws);
    u16*   Wqb = (u16*)(ws + 12582912);
    u16*   W1b = (u16*)(ws + 13762560);
    u16*   W2b = (u16*)(ws + 14024704);
    float* b1e = (float*)(ws + 14090240);
    u16*   P   = (u16*)(ws + 14092288);

    prep<<<6882, 256, 0, stream>>>(X, Xb, Wq, Wqb, W1, W1b, W2, W2b, b1, coeffs, b1e);

    // GEMM1 + poly epilogue: P = poly(clip(Xb @ Wqb^T)), K folded 256->192
    gemm1_poly<<<dim3(128, 6), 256, 0, stream>>>(Xb, Wqb, coeffs, P);

    // fused GEMM2+GEMM3: out = relu(P @ W1[64:]^T + b1e) @ W2^T + b2
    gemm23<<<dim3(768), 256, 0, stream>>>(P, W1b, b1e, W2b, b2, (float*)d_out);
}

// Round 7
// 150.958 us; speedup vs baseline: 1.1007x; 1.1007x over previous
//
#include <hip/hip_runtime.h>

// AtlasAttention v8 — single fused GEMM1+poly+MLP kernel (+prep).
// Per block (64 tokens x 2 heads = 128 flat rows):
//   phase 1: q = Xb @ Wqb^T (ring-staged, counted vmcnt) -> clipped bf16 q in LDS.
//   phase 2: GEMM2 windows build poly fragments ON THE FLY from q (ds_read +
//            ~20 VALU), W1 ring-staged; accH -> Hs -> GEMM3 (W2 frags in regs)
//            -> out (flat-row remap). No P / H through HBM at all.
//
// ws layout (bytes):
//   Xb   @ 0          : 8192*768 bf16   = 12,582,912
//   Wqb  @ 12,582,912 : 768*768  bf16^T = 1,179,648   (Wqb[n][k])
//   W1b  @ 13,762,560 : 512*256  bf16^T = 262,144     (W1b[n][k])
//   W2b  @ 14,024,704 : 64*512   bf16^T = 65,536      (W2b[m][k])
//   b1e  @ 14,090,240 : 512 f32         = 2,048

typedef unsigned short u16;
typedef __attribute__((ext_vector_type(8))) short short8;
typedef __attribute__((ext_vector_type(4))) float f32x4;
typedef __attribute__((ext_vector_type(4))) u16 u16x4;

__device__ __forceinline__ u16 f2bf(float f) {
    unsigned u = __builtin_bit_cast(unsigned, f);
    u += 0x7FFFu + ((u >> 16) & 1u);   // RNE
    return (u16)(u >> 16);
}

__device__ __forceinline__ unsigned cvtpk_bf16(float lo, float hi) {
    unsigned r;
    asm("v_cvt_pk_bf16_f32 %0, %1, %2" : "=v"(r) : "v"(lo), "v"(hi));
    return r;
}

__device__ __forceinline__ void gl2lds16(const void* g, void* l) {
    __builtin_amdgcn_global_load_lds(
        (const __attribute__((address_space(1))) unsigned int*)g,
        (__attribute__((address_space(3))) unsigned int*)l, 16, 0, 0);
}

// lgkmcnt(0) ALWAYS included: a wave's LDS reads complete before it passes a barrier.
#define WAIT_VM_LGKM_BAR(N) \
    asm volatile("s_waitcnt vmcnt(" #N ") lgkmcnt(0)\n\ts_barrier" ::: "memory")
#define WAIT_LGKM_BAR() \
    asm volatile("s_waitcnt lgkmcnt(0)\n\ts_barrier" ::: "memory")

// ---------------- fused prep kernel (unchanged, proven) ----------------
__global__ __launch_bounds__(256)
void prep(const float* __restrict__ X, u16* __restrict__ Xb,
          const float* __restrict__ Wq, u16* __restrict__ Wqb,
          const float* __restrict__ W1, u16* __restrict__ W1b,
          const float* __restrict__ W2, u16* __restrict__ W2b,
          const float* __restrict__ b1, const float* __restrict__ coeffs,
          float* __restrict__ b1e)
{
    __shared__ float t[32][33];
    const int b = blockIdx.x, tid = threadIdx.x;

    if (b < 6144) {                       // ---- cast X ----
        const int i = b * 256 + tid;
        float4 v = reinterpret_cast<const float4*>(X)[i];
        u16x4 o = {f2bf(v.x), f2bf(v.y), f2bf(v.z), f2bf(v.w)};
        reinterpret_cast<u16x4*>(Xb)[i] = o;
    } else if (b < 6880) {                // ---- transposes ----
        const float* in; u16* out; int R, Cin, bx, by;
        int lb = b - 6144;
        if (lb < 576)      { in = Wq; out = Wqb; R = 768; Cin = 768; bx = lb % 24; by = lb / 24; }
        else if (lb < 704) { lb -= 576; in = W1; out = W1b; R = 256; Cin = 512; bx = lb % 16; by = lb / 16; }
        else               { lb -= 704; in = W2; out = W2b; R = 512; Cin = 256; bx = lb % 2;  by = lb / 2; }
        const int c0 = bx * 32, r0 = by * 32;
        const int tx = tid & 31, ty = tid >> 5;
        #pragma unroll
        for (int j = 0; j < 32; j += 8)
            t[ty + j][tx] = in[(size_t)(r0 + ty + j) * Cin + c0 + tx];
        __syncthreads();
        #pragma unroll
        for (int j = 0; j < 32; j += 8)
            out[(size_t)(c0 + ty + j) * R + r0 + tx] = f2bf(t[tx][ty + j]);
    } else {                              // ---- b1e ----
        const int n = (b - 6880) * 256 + tid;
        float s = 0.f;
        #pragma unroll 8
        for (int k = 0; k < 64; ++k) s += W1[k * 512 + n];
        b1e[n] = b1[n] + coeffs[0] * s;
    }
}

// ---------------- fused kernel ----------------
// grid (128, 6), 256 threads. LDS 75,776B -> 2 blocks/CU.
//   qt    @ u16[0]     : [128][72] clipped q bf16 (cols 0..63 used, 72 kills conflicts)
//   ring1 @ u16[9216]  : phase1, 3 x 6144 (Xs[64][32] + Ws[128][32])
//   ring2 @ u16[9216]  : phase2, 3 x 4096 (W1 chunk [128][32])   (aliases ring1)
//   HsB   @ u16[21504] : 4 x 4096 (H slice, token-major, swizzled)

__global__ __launch_bounds__(256, 2)
void fused(const u16* __restrict__ Xb, const u16* __restrict__ Wqb,
           const float* __restrict__ coeffs,
           const u16* __restrict__ W1t, const float* __restrict__ b1e,
           const u16* __restrict__ W2t, const float* __restrict__ b2,
           float* __restrict__ out)
{
    __shared__ u16 shm[37888];

    const int tid = threadIdx.x;
    const int w = tid >> 6, lane = tid & 63;
    const int lrow = lane >> 2, lslot = lane & 3;
    const int m16 = lane & 15, quad = lane >> 4;
    const int w0 = w & 1, w1 = w >> 1;
    const int tok0 = blockIdx.x * 64;
    const int bn = blockIdx.y * 128;
    const int h0 = blockIdx.y * 2;

    const float c1 = coeffs[1], c2 = coeffs[2], c3 = coeffs[3];

    u16* const qt    = shm;            // [128][72]
    u16* const ring1 = shm + 9216;
    u16* const ring2 = shm + 9216;
    u16* const HsB   = shm + 21504;

    // ================= phase 1: q = Xb @ Wqb^T =================
    f32x4 acc[4][2];
    #pragma unroll
    for (int i = 0; i < 4; ++i)
        #pragma unroll
        for (int j = 0; j < 2; ++j)
            acc[i][j] = (f32x4){0.f, 0.f, 0.f, 0.f};

    auto stage1 = [&](int slot, int g) {   // 3 loads/thread
        const int k0 = g * 32;
        u16* Xs = ring1 + slot * 6144;
        u16* Ws = Xs + 2048;
        {
            const int row = w * 16 + lrow;
            const int cc = lslot ^ ((row >> 2) & 3);
            gl2lds16(Xb + (size_t)(tok0 + row) * 768 + k0 + cc * 8, &Xs[row * 32 + lslot * 8]);
        }
        #pragma unroll
        for (int i = 0; i < 2; ++i) {
            const int row = (w * 2 + i) * 16 + lrow;
            const int cc = lslot ^ ((row >> 2) & 3);
            gl2lds16(Wqb + (size_t)(bn + row) * 768 + k0 + cc * 8, &Ws[row * 32 + lslot * 8]);
        }
    };

    stage1(0, 0);
    stage1(1, 1);

    #pragma unroll 1
    for (int g = 0; g < 24; ++g) {
        WAIT_VM_LGKM_BAR(3);                          // chunk g landed; slot (g-1)%3 free
        stage1((g + 2) % 3, (g + 2 <= 23) ? g + 2 : 23);
        const u16* Xs = ring1 + (g % 3) * 6144;
        const u16* Ws = Xs + 2048;
        short8 a[4], b[2];
        #pragma unroll
        for (int i = 0; i < 4; ++i) {
            const int row = w0 * 64 + i * 16 + m16;    // n local
            const int ss = quad ^ ((row >> 2) & 3);
            a[i] = *reinterpret_cast<const short8*>(&Ws[row * 32 + ss * 8]);
        }
        #pragma unroll
        for (int j = 0; j < 2; ++j) {
            const int row = w1 * 32 + j * 16 + m16;    // token local
            const int ss = quad ^ ((row >> 2) & 3);
            b[j] = *reinterpret_cast<const short8*>(&Xs[row * 32 + ss * 8]);
        }
        __builtin_amdgcn_s_setprio(1);
        #pragma unroll
        for (int i = 0; i < 4; ++i)
            #pragma unroll
            for (int j = 0; j < 2; ++j)
                acc[i][j] = __builtin_amdgcn_mfma_f32_16x16x32_bf16(a[i], b[j], acc[i][j], 0, 0, 0);
        __builtin_amdgcn_s_setprio(0);
    }

    // phase boundary: drain ring dummies + all LDS reads, then barrier
    asm volatile("s_waitcnt vmcnt(0) lgkmcnt(0)\n\ts_barrier" ::: "memory");

    // ---- q drain: qt[l][d0..d0+3] = bf16(clip(q)), l = tokLocal*2 + head ----
    #pragma unroll
    for (int i = 0; i < 4; ++i) {
        const int d0 = i * 16 + quad * 4;
        #pragma unroll
        for (int j = 0; j < 2; ++j) {
            const int l = (w1 * 32 + j * 16 + m16) * 2 + w0;
            float x0 = fminf(fmaxf(acc[i][j][0], -10.f), 10.f);
            float x1 = fminf(fmaxf(acc[i][j][1], -10.f), 10.f);
            float x2 = fminf(fmaxf(acc[i][j][2], -10.f), 10.f);
            float x3 = fminf(fmaxf(acc[i][j][3], -10.f), 10.f);
            uint2 v;
            v.x = cvtpk_bf16(x0, x1);
            v.y = cvtpk_bf16(x2, x3);
            *reinterpret_cast<uint2*>(&qt[l * 72 + d0]) = v;
        }
    }

    // ================= phase 2: out = relu(poly(q)@W1^T + b1e) @ W2^T + b2 =======
    auto stage2 = [&](int slot, int g) {   // 2 loads/thread (W1 chunk only)
        const int s = g / 6, c = g % 6;
        u16* W1s = ring2 + slot * 4096;
        #pragma unroll
        for (int i = 0; i < 2; ++i) {
            const int row = (w * 2 + i) * 16 + lrow;
            const int cc = lslot ^ ((row >> 2) & 3);
            gl2lds16(W1t + (size_t)(s * 128 + row) * 256 + 64 + c * 32 + cc * 8,
                     &W1s[row * 32 + lslot * 8]);
        }
    };
    auto stage2c = [&](int slot, int gg) {
        if (gg <= 23) stage2(slot, gg);
        else if (gg == 24) stage2(slot, 23);   // dummy keeps vmcnt uniform
    };

    short8 b3s[4][2];                 // W2 fragments for current slice (8 vmem loads)
    auto loadW2 = [&](int s) {
        #pragma unroll
        for (int c = 0; c < 4; ++c)
            #pragma unroll
            for (int j = 0; j < 2; ++j)
                b3s[c][j] = *reinterpret_cast<const short8*>(
                    W2t + (size_t)(w1 * 32 + j * 16 + m16) * 512 + s * 128 + c * 32 + quad * 8);
    };

    f32x4 accO[4][2];
    #pragma unroll
    for (int i = 0; i < 4; ++i)
        #pragma unroll
        for (int j = 0; j < 2; ++j)
            accO[i][j] = (f32x4){0.f, 0.f, 0.f, 0.f};

    stage2(0, 0);
    stage2(1, 1);

    #pragma unroll 1
    for (int s = 0; s < 4; ++s) {
        f32x4 accH[4][4];
        #pragma unroll
        for (int i = 0; i < 4; ++i)
            #pragma unroll
            for (int j = 0; j < 4; ++j)
                accH[i][j] = (f32x4){0.f, 0.f, 0.f, 0.f};

        auto computeH = [&](int slot, int c) {
            const u16* W1s = ring2 + slot * 4096;
            short8 af[4], bf[4];
            #pragma unroll
            for (int i = 0; i < 4; ++i) {
                const int row = w0 * 64 + i * 16 + m16;          // nH local
                const int ss = quad ^ ((row >> 2) & 3);
                af[i] = *reinterpret_cast<const short8*>(&W1s[row * 32 + ss * 8]);
            }
            #pragma unroll
            for (int j = 0; j < 4; ++j) {
                const int row = w1 * 64 + j * 16 + m16;          // flat-local row
                short8 qv = *reinterpret_cast<const short8*>(
                    &qt[row * 72 + (c & 1) * 32 + quad * 8]);
                float y[8];
                #pragma unroll
                for (int e = 0; e < 8; ++e) {
                    float x = __builtin_bit_cast(float, ((unsigned)(u16)qv[e]) << 16);
                    if (c < 2)      y[e] = c1 * x;
                    else if (c < 4) y[e] = c2 * (x * x);
                    else            y[e] = (c3 * (x * x)) * x;
                }
                uint4 pk;
                pk.x = cvtpk_bf16(y[0], y[1]);
                pk.y = cvtpk_bf16(y[2], y[3]);
                pk.z = cvtpk_bf16(y[4], y[5]);
                pk.w = cvtpk_bf16(y[6], y[7]);
                bf[j] = __builtin_bit_cast(short8, pk);
            }
            __builtin_amdgcn_s_setprio(1);
            #pragma unroll
            for (int i = 0; i < 4; ++i)
                #pragma unroll
                for (int j = 0; j < 4; ++j)
                    accH[i][j] = __builtin_amdgcn_mfma_f32_16x16x32_bf16(af[i], bf[j], accH[i][j], 0, 0, 0);
            __builtin_amdgcn_s_setprio(0);
        };

        const int g0 = s * 6;
        // windows: read slot c6%3, stage slot (c6+2)%3; W2's 8 loads at c6=0 ->
        // waits [2,10,10,2,2,2] (in-order retirement: N = #vmem issued after the chunk)
        WAIT_VM_LGKM_BAR(2);  stage2c(2, g0 + 2); loadW2(s); computeH(0, 0);
        WAIT_VM_LGKM_BAR(10); stage2c(0, g0 + 3);            computeH(1, 1);
        WAIT_VM_LGKM_BAR(10); stage2c(1, g0 + 4);            computeH(2, 2);
        WAIT_VM_LGKM_BAR(2);  stage2c(2, g0 + 5);            computeH(0, 3);
        WAIT_VM_LGKM_BAR(2);  stage2c(0, g0 + 6);            computeH(1, 4);
        WAIT_VM_LGKM_BAR(2);  stage2c(1, g0 + 7);            computeH(2, 5);

        // ---- drain: Hs[tok][nH] = bf16(relu(accH + b1e)); 8B k-contiguous writes ----
        #pragma unroll
        for (int i = 0; i < 4; ++i) {
            const int lb = w0 * 64 + i * 16 + quad * 4;          // nH local base
            const f32x4 bv = *reinterpret_cast<const f32x4*>(&b1e[s * 128 + lb]);
            const int hc = lb >> 5;
            #pragma unroll
            for (int j = 0; j < 4; ++j) {
                const int tc = w1 * 64 + j * 16 + m16;           // flat-local row
                const float h0v = fmaxf(accH[i][j][0] + bv[0], 0.f);
                const float h1v = fmaxf(accH[i][j][1] + bv[1], 0.f);
                const float h2v = fmaxf(accH[i][j][2] + bv[2], 0.f);
                const float h3v = fmaxf(accH[i][j][3] + bv[3], 0.f);
                uint2 v;
                v.x = cvtpk_bf16(h0v, h1v);
                v.y = cvtpk_bf16(h2v, h3v);
                const int sl = ((lb >> 3) & 3) ^ ((tc >> 2) & 3);
                *reinterpret_cast<uint2*>(&HsB[hc * 4096 + tc * 32 + sl * 8 + (lb & 7)]) = v;
            }
        }

        WAIT_LGKM_BAR();   // Hs visible; ring prefetches stay in flight

        // ---- GEMM3 partial: accO += Hs @ W2slice^T ----
        __builtin_amdgcn_s_setprio(1);
        #pragma unroll
        for (int c = 0; c < 4; ++c) {
            short8 a3[4];
            #pragma unroll
            for (int i = 0; i < 4; ++i) {
                const int tr = w0 * 64 + i * 16 + m16;           // flat-local row
                const int ss = quad ^ ((tr >> 2) & 3);
                a3[i] = *reinterpret_cast<const short8*>(&HsB[c * 4096 + tr * 32 + ss * 8]);
            }
            #pragma unroll
            for (int i = 0; i < 4; ++i)
                #pragma unroll
                for (int j = 0; j < 2; ++j)
                    accO[i][j] = __builtin_amdgcn_mfma_f32_16x16x32_bf16(a3[i], b3s[c][j], accO[i][j], 0, 0, 0);
        }
        __builtin_amdgcn_s_setprio(0);
        // next slice's first WAIT (lgkm 0 + barrier) orders these ds_reads vs next drain
    }

    asm volatile("s_waitcnt vmcnt(0)" ::: "memory");   // retire dummy stages

    // ---- epilogue: out[(tok0 + l/2)*12 + h0 + (l&1)][col] = accO + b2 ----
    #pragma unroll
    for (int j = 0; j < 2; ++j) {
        const int col = w1 * 32 + j * 16 + m16;
        const float bv = b2[col];
        #pragma unroll
        for (int i = 0; i < 4; ++i) {
            #pragma unroll
            for (int r = 0; r < 4; ++r) {
                const int l = w0 * 64 + i * 16 + quad * 4 + r;
                const size_t orow = (size_t)(tok0 + (l >> 1)) * 12 + h0 + (l & 1);
                out[orow * 64 + col] = accO[i][j][r] + bv;
            }
        }
    }
}

// ---------------- host ----------------

extern "C" void kernel_launch(void* const* d_in, const int* in_sizes, int n_in,
                              void* d_out, int out_size, void* d_ws, size_t ws_size,
                              hipStream_t stream) {
    const float* X      = (const float*)d_in[0];
    const float* Wq     = (const float*)d_in[1];
    const float* coeffs = (const float*)d_in[2];
    const float* W1     = (const float*)d_in[3];
    const float* b1     = (const float*)d_in[4];
    const float* W2     = (const float*)d_in[5];
    const float* b2     = (const float*)d_in[6];

    char* ws = (char*)d_ws;
    u16*   Xb  = (u16*)(ws);
    u16*   Wqb = (u16*)(ws + 12582912);
    u16*   W1b = (u16*)(ws + 13762560);
    u16*   W2b = (u16*)(ws + 14024704);
    float* b1e = (float*)(ws + 14090240);

    prep<<<6882, 256, 0, stream>>>(X, Xb, Wq, Wqb, W1, W1b, W2, W2b, b1, coeffs, b1e);

    // one fused kernel: q -> poly (on the fly) -> MLP -> out
    fused<<<dim3(128, 6), 256, 0, stream>>>(Xb, Wqb, coeffs, W1b, b1e, W2b, b2,
                                            (float*)d_out);
}